// Round 14
// baseline (294.301 us; speedup 1.0000x reference)
//
#include <hip/hip_runtime.h>
#include <math.h>

#define WAY 5
#define SHOT 5
#define HEADS 12
#define DIM 768
#define LSEQ 512
#define HD 64
#define NROWS (WAY*SHOT*LSEQ)   // 12800
#define SCALE 0.125f
#define NXEL ((size_t)NROWS*DIM)
#define NWEL ((size_t)DIM*DIM)

typedef __attribute__((ext_vector_type(8))) short short8;
typedef __attribute__((ext_vector_type(4))) float f32x4;
typedef __attribute__((ext_vector_type(4))) unsigned short ushort4v;

__device__ __forceinline__ float bf2f(unsigned short u) {
    union { unsigned int i; float f; } x; x.i = ((unsigned int)u) << 16; return x.f;
}
__device__ __forceinline__ unsigned short f2bf(float f) {
    union { float f; unsigned int i; } x; x.f = f;
    unsigned int r = x.i + 0x7FFFu + ((x.i >> 16) & 1u);
    return (unsigned short)(r >> 16);
}

// ---------------------------------------------------------------------------
// K0: all fp32->bf16 casts in one launch.
// ---------------------------------------------------------------------------
#define NX4 (NROWS*DIM/4)
#define NW4 (DIM*DIM/4)
__global__ __launch_bounds__(256) void cast_all(
    const float* __restrict__ X, const float* __restrict__ Wq,
    const float* __restrict__ Wk, const float* __restrict__ Wv,
    unsigned short* __restrict__ Xb, unsigned short* __restrict__ Wb)
{
    int i = blockIdx.x * 256 + threadIdx.x;
    const float* s; unsigned short* d; int off;
    if (i < NX4)               { s = X;  d = Xb;            off = i; }
    else if (i < NX4 + NW4)    { s = Wq; d = Wb;            off = i - NX4; }
    else if (i < NX4 + 2*NW4)  { s = Wk; d = Wb + NWEL;     off = i - NX4 - NW4; }
    else if (i < NX4 + 3*NW4)  { s = Wv; d = Wb + 2*NWEL;   off = i - NX4 - 2*NW4; }
    else return;
    float4 f = ((const float4*)s)[off];
    ushort4v o;
    o.x = f2bf(f.x); o.y = f2bf(f.y); o.z = f2bf(f.z); o.w = f2bf(f.w);
    *(ushort4v*)(d + (size_t)off*4) = o;
}

// ---------------------------------------------------------------------------
// K1: fused QKV projection as ONE folded GEMM: C[12800][2304] = Xb * Wcat^T.
// 128x128 tile, BK=64, 4 waves, K-loop fully unrolled, LDS dbuf issue-early,
// coalesced epilogue via LDS repack.  T1 XCD swizzle + T2 XOR swizzle.
// grid = 1800, block = 256.  (frozen — best measured config)
// ---------------------------------------------------------------------------
__global__ __launch_bounds__(256) void qkv_mfma(
    const unsigned short* __restrict__ Xb, const unsigned short* __restrict__ Wball,
    const float* __restrict__ bq, const float* __restrict__ bk, const float* __restrict__ bv,
    unsigned short* __restrict__ qkv_out)
{
    // ---- T1 XCD swizzle: nwg=1800, 8 XCDs, 225 blocks per XCD, m-major ----
    const int bid  = blockIdx.x;
    const int sw   = (bid & 7) * 225 + (bid >> 3);
    const int mblk = sw / 18;
    const int nblk = sw - mblk * 18;
    const int m0   = mblk * 128;
    const int n0g  = nblk * 128;
    const int which = n0g / DIM;
    const int n0    = n0g - which * DIM;

    const unsigned short* W = Wball + (size_t)n0g * DIM;
    const float* bias = (which == 0) ? bq : ((which == 1) ? bk : bv);
    unsigned short* out = qkv_out + (size_t)which * NXEL;

    // [0]=A0 [1]=B0 [2]=A1 [3]=B1 ; whole 64KB reused as C[128][136] epilogue
    __shared__ __align__(16) unsigned short Sm[4][128*64];

    const int t = threadIdx.x;
    const int w = t >> 6;
    const int lane = t & 63;
    const int quad = lane >> 4;
    const int l15 = lane & 15;
    const int wm = (w & 1) * 64;
    const int wn = (w >> 1) * 64;

    const int srow   = lane >> 3;
    const int gchunk = (lane & 7) ^ srow;

    const unsigned short* gAbase = Xb + (size_t)(m0 + w*32 + srow)*DIM + gchunk*8;
    const unsigned short* gBbase = W  + (size_t)(w*32 + srow)*DIM      + gchunk*8;

    f32x4 acc[4][4];
    #pragma unroll
    for (int i = 0; i < 4; i++)
        #pragma unroll
        for (int j = 0; j < 4; j++)
            acc[i][j] = (f32x4){0.f, 0.f, 0.f, 0.f};

    #define STAGE(KT, BUF)                                                        \
        {                                                                         \
            _Pragma("unroll")                                                     \
            for (int c = 0; c < 4; c++) {                                         \
                __builtin_amdgcn_global_load_lds(                                 \
                    (const __attribute__((address_space(1))) unsigned int*)       \
                        (gAbase + (size_t)(c*8)*DIM + (KT)*64),                   \
                    (__attribute__((address_space(3))) unsigned int*)             \
                        &Sm[(BUF)*2][(w*32 + c*8)*64], 16, 0, 0);                 \
                __builtin_amdgcn_global_load_lds(                                 \
                    (const __attribute__((address_space(1))) unsigned int*)       \
                        (gBbase + (size_t)(c*8)*DIM + (KT)*64),                   \
                    (__attribute__((address_space(3))) unsigned int*)             \
                        &Sm[(BUF)*2 + 1][(w*32 + c*8)*64], 16, 0, 0);             \
            }                                                                     \
        }

    STAGE(0, 0);
    __syncthreads();

    #pragma unroll
    for (int kt = 0; kt < 12; ++kt) {
        if (kt + 1 < 12) STAGE(kt + 1, (kt + 1) & 1);

        const unsigned short* As = &Sm[(kt & 1) * 2][0];
        const unsigned short* Bs = &Sm[(kt & 1) * 2 + 1][0];

        #pragma unroll
        for (int kk = 0; kk < 2; kk++) {
            const int ch = kk*4 + quad;
            short8 af[4], bf_[4];
            #pragma unroll
            for (int i = 0; i < 4; i++) {
                const int row = wm + i*16 + l15;
                af[i]  = *(const short8*)&As[row*64 + ((ch ^ (row & 7)) << 3)];
            }
            #pragma unroll
            for (int j = 0; j < 4; j++) {
                const int row = wn + j*16 + l15;
                bf_[j] = *(const short8*)&Bs[row*64 + ((ch ^ (row & 7)) << 3)];
            }
            #pragma unroll
            for (int i = 0; i < 4; i++)
                #pragma unroll
                for (int j = 0; j < 4; j++)
                    acc[i][j] = __builtin_amdgcn_mfma_f32_16x16x32_bf16(af[i], bf_[j], acc[i][j], 0, 0, 0);
        }
        __syncthreads();
    }
    #undef STAGE

    // ---- epilogue: acc(+bias) -> LDS [128][136] -> coalesced 16B stores ----
    unsigned short* Cs = &Sm[0][0];
    #pragma unroll
    for (int j = 0; j < 4; j++) {
        const int col = wn + j*16 + l15;
        const float bv_ = bias[n0 + col];
        #pragma unroll
        for (int i = 0; i < 4; i++) {
            #pragma unroll
            for (int r = 0; r < 4; r++) {
                const int row = wm + i*16 + quad*4 + r;
                Cs[row*136 + col] = f2bf(acc[i][j][r] + bv_);
            }
        }
    }
    __syncthreads();
    #pragma unroll
    for (int u = 0; u < 8; u++) {
        const int idx = u*256 + t;
        const int row = idx >> 4, ch = idx & 15;
        short8 v = *(const short8*)&Cs[row*136 + ch*8];
        *(short8*)&out[(size_t)(m0 + row)*DIM + n0 + ch*8] = v;
    }
}

// XOR-swizzled LDS addressing for 64x64-ushort tiles.
__device__ __forceinline__ int swz(int row, int u) {
    return row*64 + ((u ^ (row & 7)) << 3);
}

// ---------------------------------------------------------------------------
// K2: branch-1 token attention (grid=(300,8)).
// V-staging flipped from scatter-READ to scatter-WRITE: V rows loaded with
// the same coalesced 2x short8 pattern as K; transpose happens as 8x
// ds_write_u16 per load into the swizzled Vt layout (32-bit LDS addressing,
// no vmcnt, <=4-way bank alias on the cheap LDS pipe).  Replaces 16 scalar
// global load_ushort per thread per kt (the 52% VALUBusy).
// ---------------------------------------------------------------------------
__global__ __launch_bounds__(256) void attn1_mfma(
    const unsigned short* __restrict__ qb, const unsigned short* __restrict__ kb,
    const unsigned short* __restrict__ vb, float* __restrict__ a1p)
{
    int whs = blockIdx.x;
    const int chunk = blockIdx.y;
    const int si = whs % SHOT;  whs /= SHOT;
    const int hi = whs % HEADS; whs /= HEADS;
    const int wi = whs;
    const size_t baseRow = (size_t)(wi*SHOT + si) * LSEQ;
    const int colBase = hi * HD;

    __shared__ __align__(16) unsigned short Qs[64*64];
    __shared__ __align__(16) unsigned short Ks[64*64];
    __shared__ __align__(16) unsigned short Vt[64*64];
    __shared__ __align__(16) unsigned short Pb[64*64];
    __shared__ float cmaxs[4][64];

    const int t = threadIdx.x;
    const int w = t >> 6;
    const int lane = t & 63;
    const int quad = lane >> 4;
    const int l15 = lane & 15;

    #pragma unroll
    for (int p = 0; p < 2; p++) {
        int idx = p*256 + t;
        int row = idx >> 3, u = idx & 7;
        *(short8*)&Qs[swz(row, u)] =
            *(const short8*)&qb[(baseRow + chunk*64 + row)*DIM + colBase + u*8];
    }

    float l_part[4] = {0.f, 0.f, 0.f, 0.f};   // per-lane partial row sums
    f32x4 o_acc[4];
    #pragma unroll
    for (int d = 0; d < 4; d++) o_acc[d] = (f32x4){0.f, 0.f, 0.f, 0.f};

    for (int kt = 0; kt < 8; kt++) {
        __syncthreads();
        #pragma unroll
        for (int p = 0; p < 2; p++) {
            int idx = p*256 + t;
            int row = idx >> 3, u = idx & 7;
            *(short8*)&Ks[swz(row, u)] =
                *(const short8*)&kb[(baseRow + kt*64 + row)*DIM + colBase + u*8];
        }
        // V: coalesced short8 row load + 8-way LDS scatter into Vt[d][l].
        // Vt element (d, l) lives at swz(d, l>>3) + (l&7); here d = u*8+j,
        // l = row, and (d&7) == j.
        #pragma unroll
        for (int p = 0; p < 2; p++) {
            int idx = p*256 + t;
            int row = idx >> 3, u = idx & 7;   // row = l, u = d-oct
            short8 v8 = *(const short8*)&vb[(baseRow + kt*64 + row)*DIM + colBase + u*8];
            const int rhi = row >> 3, rlo = row & 7;
            #pragma unroll
            for (int j = 0; j < 8; j++)
                Vt[(u*8 + j)*64 + ((rhi ^ j) << 3) + rlo] = (unsigned short)v8[j];
        }
        __syncthreads();

        // S = Q K^T
        f32x4 s_acc[4];
        #pragma unroll
        for (int nt = 0; nt < 4; nt++) s_acc[nt] = (f32x4){0.f, 0.f, 0.f, 0.f};
        short8 aq[2];
        #pragma unroll
        for (int kk = 0; kk < 2; kk++)
            aq[kk] = *(const short8*)&Qs[swz(w*16 + l15, kk*4 + quad)];
        #pragma unroll
        for (int kk = 0; kk < 2; kk++) {
            #pragma unroll
            for (int nt = 0; nt < 4; nt++) {
                short8 bk_ = *(const short8*)&Ks[swz(nt*16 + l15, kk*4 + quad)];
                s_acc[nt] = __builtin_amdgcn_mfma_f32_16x16x32_bf16(aq[kk], bk_, s_acc[nt], 0, 0, 0);
            }
        }

        // e = exp(s*SCALE), no max-subtraction; accumulate per-lane row sums
        #pragma unroll
        for (int nt = 0; nt < 4; nt++) {
            #pragma unroll
            for (int r = 0; r < 4; r++) {
                float e = __expf(s_acc[nt][r] * SCALE);
                s_acc[nt][r] = e;
                l_part[r] += e;
            }
        }

        // write P (bf16) into wave-private Pb rows
        #pragma unroll
        for (int nt = 0; nt < 4; nt++) {
            int ucol = nt*2 + (l15 >> 3);
            int cofs = l15 & 7;
            #pragma unroll
            for (int r = 0; r < 4; r++) {
                int row = w*16 + quad*4 + r;
                Pb[swz(row, ucol) + cofs] = f2bf(s_acc[nt][r]);
            }
        }

        // O += P V
        short8 ap[2];
        #pragma unroll
        for (int kk = 0; kk < 2; kk++)
            ap[kk] = *(const short8*)&Pb[swz(w*16 + l15, kk*4 + quad)];
        #pragma unroll
        for (int kk = 0; kk < 2; kk++) {
            #pragma unroll
            for (int dt = 0; dt < 4; dt++) {
                short8 bv_ = *(const short8*)&Vt[swz(dt*16 + l15, kk*4 + quad)];
                o_acc[dt] = __builtin_amdgcn_mfma_f32_16x16x32_bf16(ap[kk], bv_, o_acc[dt], 0, 0, 0);
            }
        }
    }

    // single end-of-block row-sum reduction over the 16 lanes sharing quad
    float l_tot[4];
    #pragma unroll
    for (int r = 0; r < 4; r++) {
        float s = l_part[r];
        #pragma unroll
        for (int off = 1; off < 16; off <<= 1) s += __shfl_xor(s, off);
        l_tot[r] = s;
    }

    float cm[4];
    #pragma unroll
    for (int dt = 0; dt < 4; dt++) {
        float mx = -1e30f;
        #pragma unroll
        for (int r = 0; r < 4; r++) mx = fmaxf(mx, o_acc[dt][r] / l_tot[r]);
        mx = fmaxf(mx, __shfl_xor(mx, 16));
        mx = fmaxf(mx, __shfl_xor(mx, 32));
        cm[dt] = mx;
    }
    if (quad == 0) {
        #pragma unroll
        for (int dt = 0; dt < 4; dt++) cmaxs[w][dt*16 + l15] = cm[dt];
    }
    __syncthreads();
    if (t < 64) {
        float mx = fmaxf(fmaxf(cmaxs[0][t], cmaxs[1][t]), fmaxf(cmaxs[2][t], cmaxs[3][t]));
        a1p[((size_t)((wi*HEADS + hi)*SHOT + si)*8 + chunk)*64 + t] = mx;
    }
}

// ---------------------------------------------------------------------------
// K3a: branch-2 scores: one block per (wh, si, tt) pair, grid = 1500,
// block = 256, direct pre-scaled SSC output.
// ---------------------------------------------------------------------------
__global__ __launch_bounds__(256) void attn2_scores(
    const unsigned short* __restrict__ qb, const unsigned short* __restrict__ kb,
    float* __restrict__ SSC)
{
    const int bid = blockIdx.x;          // 0..1499
    const int wh = bid / 25, pr = bid % 25;
    const int wi = wh / HEADS, hi = wh % HEADS;
    const int si = pr / 5, tt = pr % 5;
    const int t = threadIdx.x;
    const int w = t >> 6, lane = t & 63;
    const int doct = lane & 7;
    const int lgrp = w*8 + (lane >> 3);   // 0..31
    const int colB = hi*HD + doct*8;

    const unsigned short* qrow = qb + (size_t)(wi*SHOT+si)*LSEQ*DIM + colB;
    const unsigned short* krow = kb + (size_t)(wi*SHOT+tt)*LSEQ*DIM + colB;

    float acc[8] = {};
    #pragma unroll
    for (int it = 0; it < 16; it++) {
        const int l = lgrp + it*32;
        short8 q8 = *(const short8*)(qrow + (size_t)l*DIM);
        short8 k8 = *(const short8*)(krow + (size_t)l*DIM);
        #pragma unroll
        for (int j = 0; j < 8; j++)
            acc[j] += bf2f((unsigned short)q8[j]) * bf2f((unsigned short)k8[j]);
    }
    // intra-wave reduce across the 8 lgrp slots sharing a doct
    #pragma unroll
    for (int off = 8; off < 64; off <<= 1)
        #pragma unroll
        for (int j = 0; j < 8; j++)
            acc[j] += __shfl_xor(acc[j], off);

    __shared__ float ws[4][8][8];
    if (lane < 8) {
        #pragma unroll
        for (int j = 0; j < 8; j++) ws[w][lane][j] = acc[j];
    }
    __syncthreads();
    if (t < 64) {
        const int dct = t >> 3, j = t & 7;
        float s = ws[0][dct][j] + ws[1][dct][j] + ws[2][dct][j] + ws[3][dct][j];
        SSC[(size_t)(wh*25 + pr)*64 + dct*8 + j] = s * SCALE;
    }
}

// ---------------------------------------------------------------------------
// K3b: finish softmax + partial weighted-max.  grid=(60,8), block=320.
// ---------------------------------------------------------------------------
__global__ __launch_bounds__(320) void attn2_pmax(
    const float* __restrict__ SSC, const unsigned short* __restrict__ vb,
    float* __restrict__ P2)
{
    const int wh = blockIdx.x, ch = blockIdx.y;
    const int wi = wh / HEADS, hi = wh % HEADS;
    const int t = threadIdx.x;
    const int si = t / 64;
    const int r  = t & 63;
    const int doct = r >> 3, lsub = r & 7;

    __shared__ float ssc[SHOT*SHOT*HD];   // scaled scores [si][tt][d]

    for (int e = t; e < SHOT*SHOT*HD; e += 320)
        ssc[e] = SSC[(size_t)wh*(SHOT*SHOT*HD) + e];
    __syncthreads();

    // softmax over tt (scores tiny -> no max subtraction)
    float wgt[SHOT][8];
    #pragma unroll
    for (int j = 0; j < 8; j++) {
        const int d = doct*8 + j;
        float sum = 0.f;
        #pragma unroll
        for (int tt = 0; tt < SHOT; tt++) {
            float e = __expf(ssc[(si*SHOT + tt)*HD + d]);
            wgt[tt][j] = e; sum += e;
        }
        const float inv = 1.f / sum;
        #pragma unroll
        for (int tt = 0; tt < SHOT; tt++) wgt[tt][j] *= inv;
    }

    const int colB = hi*HD + doct*8;
    float m[8];
    #pragma unroll
    for (int j = 0; j < 8; j++) m[j] = -1e30f;

    #pragma unroll 4
    for (int lc = 0; lc < 8; lc++) {
        const int l = ch*64 + lsub*8 + lc;
        float val[8] = {};
        #pragma unroll
        for (int tt = 0; tt < SHOT; tt++) {
            short8 v8 = *(const short8*)(vb + ((size_t)(wi*SHOT+tt)*LSEQ + l)*DIM + colB);
            #pragma unroll
            for (int j = 0; j < 8; j++)
                val[j] += wgt[tt][j] * bf2f((unsigned short)v8[j]);
        }
        #pragma unroll
        for (int j = 0; j < 8; j++) m[j] = fmaxf(m[j], val[j]);
    }

    #pragma unroll
    for (int off = 1; off < 8; off <<= 1)
        #pragma unroll
        for (int j = 0; j < 8; j++) m[j] = fmaxf(m[j], __shfl_xor(m[j], off));

    if (lsub == 0) {
        #pragma unroll
        for (int j = 0; j < 8; j++)
            P2[((size_t)(wh*SHOT + si)*64 + doct*8 + j)*8 + ch] = m[j];
    }
}

// ---------------------------------------------------------------------------
// K4: per-(w,s) chunk-max reduce + dual LN + tanh + wp-dot.  grid=25.
// P2 chunk-max vectorized as 2x float4.
// ---------------------------------------------------------------------------
__global__ __launch_bounds__(256) void combine(
    const float* __restrict__ a1p, const float* __restrict__ P2,
    const float* __restrict__ gamma, const float* __restrict__ beta,
    const float* __restrict__ wp, const float* __restrict__ bp,
    float* __restrict__ attn_ws, float* __restrict__ logits)
{
    const int wi = blockIdx.x / SHOT;
    const int si = blockIdx.x % SHOT;
    const int t  = threadIdx.x;

    __shared__ float row1[DIM];
    __shared__ float row2[DIM];
    __shared__ float rbuf[4][4];

    for (int j = t; j < DIM; j += 256) {
        int h = j / HD, d = j % HD;
        const float* p1 = a1p + ((size_t)((wi*HEADS + h)*SHOT + si) * 8) * 64 + d;
        float mx = -1e30f;
        #pragma unroll
        for (int c = 0; c < 8; c++) mx = fmaxf(mx, p1[c * 64]);
        row1[j] = mx;
        const float4* p2v = (const float4*)(P2 + ((size_t)((wi*HEADS + h)*SHOT + si)*64 + d)*8);
        const float4 pa = p2v[0], pb = p2v[1];
        float mx2 = fmaxf(fmaxf(fmaxf(pa.x, pa.y), fmaxf(pa.z, pa.w)),
                          fmaxf(fmaxf(pb.x, pb.y), fmaxf(pb.z, pb.w)));
        row2[j] = mx2;
    }
    __syncthreads();

    float s1 = 0, q1 = 0, s2 = 0, q2 = 0;
    for (int j = t; j < DIM; j += 256) {
        float x1 = row1[j]; s1 += x1; q1 += x1*x1;
        float x2 = row2[j]; s2 += x2; q2 += x2*x2;
    }
    #pragma unroll
    for (int off = 32; off > 0; off >>= 1) {
        s1 += __shfl_down(s1, off); q1 += __shfl_down(q1, off);
        s2 += __shfl_down(s2, off); q2 += __shfl_down(q2, off);
    }
    const int wid = t / 64, lane = t % 64;
    if (lane == 0) { rbuf[wid][0] = s1; rbuf[wid][1] = q1; rbuf[wid][2] = s2; rbuf[wid][3] = q2; }
    __syncthreads();
    if (t == 0) {
        float a = 0, b = 0, c = 0, dd = 0;
        #pragma unroll
        for (int i = 0; i < 4; i++) { a += rbuf[i][0]; b += rbuf[i][1]; c += rbuf[i][2]; dd += rbuf[i][3]; }
        rbuf[0][0] = a; rbuf[0][1] = b; rbuf[0][2] = c; rbuf[0][3] = dd;
    }
    __syncthreads();
    const float mean1 = rbuf[0][0] / (float)DIM;
    const float var1  = rbuf[0][1] / (float)DIM - mean1*mean1;
    const float mean2 = rbuf[0][2] / (float)DIM;
    const float var2  = rbuf[0][3] / (float)DIM - mean2*mean2;
    const float inv1 = rsqrtf(var1 + 1e-5f);
    const float inv2 = rsqrtf(var2 + 1e-5f);

    float dotp = 0.0f;
    for (int j = t; j < DIM; j += 256) {
        float v1 = (row1[j] - mean1) * inv1 * gamma[j] + beta[j];
        float v2 = (row2[j] - mean2) * inv2 * gamma[j] + beta[j];
        float at = 0.5f * (v1 + v2);
        attn_ws[(size_t)(wi*SHOT + si) * DIM + j] = at;
        dotp += tanhf(at) * wp[j];
    }
    #pragma unroll
    for (int off = 32; off > 0; off >>= 1) dotp += __shfl_down(dotp, off);
    __syncthreads();
    if (lane == 0) rbuf[wid][0] = dotp;
    __syncthreads();
    if (t == 0)
        logits[wi*SHOT + si] = rbuf[0][0] + rbuf[1][0] + rbuf[2][0] + rbuf[3][0] + bp[0];
}

// ---------------------------------------------------------------------------
// K5: shot-softmax + folded output projection.  grid = 192 x 256.
// ---------------------------------------------------------------------------
__global__ __launch_bounds__(256) void outproj(
    const float* __restrict__ attn_ws, const float* __restrict__ logits,
    const float* __restrict__ Wo, const float* __restrict__ bo,
    float* __restrict__ out)
{
    const int t = threadIdx.x;
    __shared__ __align__(16) float P[WAY][DIM];

    // shot-softmax weights (all threads compute all 25; logits broadcast via L1)
    float swt[WAY][SHOT];
    #pragma unroll
    for (int w5 = 0; w5 < WAY; w5++) {
        float lg[SHOT];
        float mx = -1e30f;
        #pragma unroll
        for (int s = 0; s < SHOT; s++) { lg[s] = logits[w5*SHOT + s]; mx = fmaxf(mx, lg[s]); }
        float sum = 0.f;
        #pragma unroll
        for (int s = 0; s < SHOT; s++) { lg[s] = __expf(lg[s] - mx); sum += lg[s]; }
        const float inv = 1.f / sum;
        #pragma unroll
        for (int s = 0; s < SHOT; s++) swt[w5][s] = lg[s] * inv;
    }

    // stage weighted prototypes: P[w][d] = sum_s swt[w][s] * attn_ws[w*5+s][d]
    #pragma unroll
    for (int c = 0; c < 3; c++) {
        const int d = c*256 + t;
        #pragma unroll
        for (int w5 = 0; w5 < WAY; w5++) {
            float a = 0.f;
            #pragma unroll
            for (int s = 0; s < SHOT; s++)
                a += swt[w5][s] * attn_ws[(size_t)(w5*SHOT + s)*DIM + d];
            P[w5][d] = a;
        }
    }
    __syncthreads();

    // each wave: one output column j, dotted against all 5 ways
    const int wid = t >> 6, lane = t & 63;
    const int j = blockIdx.x * 4 + wid;   // 192*4 = 768

    float acc[WAY] = {0.f, 0.f, 0.f, 0.f, 0.f};
    #pragma unroll
    for (int c = 0; c < 3; c++) {
        const int d = c*256 + lane*4;
        const float4 wo = *(const float4*)&Wo[(size_t)j*DIM + d];
        #pragma unroll
        for (int w5 = 0; w5 < WAY; w5++) {
            const float4 p = *(const float4*)&P[w5][d];
            acc[w5] += p.x*wo.x + p.y*wo.y + p.z*wo.z + p.w*wo.w;
        }
    }
    #pragma unroll
    for (int off = 32; off > 0; off >>= 1)
        #pragma unroll
        for (int w5 = 0; w5 < WAY; w5++)
            acc[w5] += __shfl_down(acc[w5], off);

    if (lane == 0) {
        const float b5 = 5.0f * bo[j];
        #pragma unroll
        for (int w5 = 0; w5 < WAY; w5++)
            out[(size_t)w5*DIM + j] = acc[w5] + b5;
    }
}

// ---------------------------------------------------------------------------
extern "C" void kernel_launch(void* const* d_in, const int* in_sizes, int n_in,
                              void* d_out, int out_size, void* d_ws, size_t ws_size,
                              hipStream_t stream) {
    const float* X     = (const float*)d_in[0];
    const float* Wq    = (const float*)d_in[1];
    const float* bq    = (const float*)d_in[2];
    const float* Wk    = (const float*)d_in[3];
    const float* bk    = (const float*)d_in[4];
    const float* Wv    = (const float*)d_in[5];
    const float* bv    = (const float*)d_in[6];
    const float* gamma = (const float*)d_in[7];
    const float* beta  = (const float*)d_in[8];
    const float* wp    = (const float*)d_in[9];
    const float* bp    = (const float*)d_in[10];
    const float* Wo    = (const float*)d_in[11];
    const float* bo    = (const float*)d_in[12];
    float* out = (float*)d_out;

    unsigned short* Xb   = (unsigned short*)d_ws;
    unsigned short* Wb   = Xb + NXEL;
    unsigned short* qkvb = Wb + 3*NWEL;
    unsigned short* qb = qkvb;
    unsigned short* kb = qkvb + NXEL;
    unsigned short* vb = qkvb + 2*NXEL;

    float* a1p    = (float*)(qkvb + 3*NXEL);
    float* SSC    = a1p + (size_t)WAY*HEADS*SHOT*8*64;
    float* P2     = SSC + (size_t)WAY*HEADS*SHOT*SHOT*64*8;
    float* attn_b = P2 + (size_t)WAY*HEADS*SHOT*64*8;
    float* logits = attn_b + (size_t)WAY*SHOT*DIM;

    // K0: one cast launch
    const int castN = NX4 + 3*NW4;
    cast_all<<<(castN + 255)/256, 256, 0, stream>>>(X, Wq, Wk, Wv, Xb, Wb);

    // K1: QKV projection
    qkv_mfma<<<1800, 256, 0, stream>>>(Xb, Wb, bq, bk, bv, qkvb);

    // K2: branch-1 attention (LDS-scatter V staging)
    dim3 g2(WAY*HEADS*SHOT, 8);
    attn1_mfma<<<g2, 256, 0, stream>>>(qb, kb, vb, a1p);

    // K3: branch-2 attention
    attn2_scores<<<1500, 256, 0, stream>>>(qb, kb, SSC);
    dim3 g3(WAY*HEADS, 8);
    attn2_pmax<<<g3, 320, 0, stream>>>(SSC, vb, P2);

    // K4/K5
    combine<<<WAY*SHOT, 256, 0, stream>>>(a1p, P2, gamma, beta, wp, bp, attn_b, logits);
    outproj<<<192, 256, 0, stream>>>(attn_b, logits, Wo, bo, out);
}

// Round 15
// 261.890 us; speedup vs baseline: 1.1238x; 1.1238x over previous
//
#include <hip/hip_runtime.h>
#include <math.h>

#define WAY 5
#define SHOT 5
#define HEADS 12
#define DIM 768
#define LSEQ 512
#define HD 64
#define NROWS (WAY*SHOT*LSEQ)   // 12800
#define SCALE 0.125f
#define NXEL ((size_t)NROWS*DIM)
#define NWEL ((size_t)DIM*DIM)

typedef __attribute__((ext_vector_type(8))) short short8;
typedef __attribute__((ext_vector_type(4))) float f32x4;
typedef __attribute__((ext_vector_type(4))) unsigned short ushort4v;

__device__ __forceinline__ float bf2f(unsigned short u) {
    union { unsigned int i; float f; } x; x.i = ((unsigned int)u) << 16; return x.f;
}
__device__ __forceinline__ unsigned short f2bf(float f) {
    union { float f; unsigned int i; } x; x.f = f;
    unsigned int r = x.i + 0x7FFFu + ((x.i >> 16) & 1u);
    return (unsigned short)(r >> 16);
}

// ---------------------------------------------------------------------------
// K0: all fp32->bf16 casts in one launch.
// ---------------------------------------------------------------------------
#define NX4 (NROWS*DIM/4)
#define NW4 (DIM*DIM/4)
__global__ __launch_bounds__(256) void cast_all(
    const float* __restrict__ X, const float* __restrict__ Wq,
    const float* __restrict__ Wk, const float* __restrict__ Wv,
    unsigned short* __restrict__ Xb, unsigned short* __restrict__ Wb)
{
    int i = blockIdx.x * 256 + threadIdx.x;
    const float* s; unsigned short* d; int off;
    if (i < NX4)               { s = X;  d = Xb;            off = i; }
    else if (i < NX4 + NW4)    { s = Wq; d = Wb;            off = i - NX4; }
    else if (i < NX4 + 2*NW4)  { s = Wk; d = Wb + NWEL;     off = i - NX4 - NW4; }
    else if (i < NX4 + 3*NW4)  { s = Wv; d = Wb + 2*NWEL;   off = i - NX4 - 2*NW4; }
    else return;
    float4 f = ((const float4*)s)[off];
    ushort4v o;
    o.x = f2bf(f.x); o.y = f2bf(f.y); o.z = f2bf(f.z); o.w = f2bf(f.w);
    *(ushort4v*)(d + (size_t)off*4) = o;
}

// ---------------------------------------------------------------------------
// K1: fused QKV projection as ONE folded GEMM: C[12800][2304] = Xb * Wcat^T.
// 128x128 tile, BK=64, 4 waves, K-loop fully unrolled, LDS dbuf issue-early,
// coalesced epilogue via LDS repack.  T1 XCD swizzle + T2 XOR swizzle.
// grid = 1800, block = 256.  (frozen — best measured config)
// ---------------------------------------------------------------------------
__global__ __launch_bounds__(256) void qkv_mfma(
    const unsigned short* __restrict__ Xb, const unsigned short* __restrict__ Wball,
    const float* __restrict__ bq, const float* __restrict__ bk, const float* __restrict__ bv,
    unsigned short* __restrict__ qkv_out)
{
    // ---- T1 XCD swizzle: nwg=1800, 8 XCDs, 225 blocks per XCD, m-major ----
    const int bid  = blockIdx.x;
    const int sw   = (bid & 7) * 225 + (bid >> 3);
    const int mblk = sw / 18;
    const int nblk = sw - mblk * 18;
    const int m0   = mblk * 128;
    const int n0g  = nblk * 128;
    const int which = n0g / DIM;
    const int n0    = n0g - which * DIM;

    const unsigned short* W = Wball + (size_t)n0g * DIM;
    const float* bias = (which == 0) ? bq : ((which == 1) ? bk : bv);
    unsigned short* out = qkv_out + (size_t)which * NXEL;

    // [0]=A0 [1]=B0 [2]=A1 [3]=B1 ; whole 64KB reused as C[128][136] epilogue
    __shared__ __align__(16) unsigned short Sm[4][128*64];

    const int t = threadIdx.x;
    const int w = t >> 6;
    const int lane = t & 63;
    const int quad = lane >> 4;
    const int l15 = lane & 15;
    const int wm = (w & 1) * 64;
    const int wn = (w >> 1) * 64;

    const int srow   = lane >> 3;
    const int gchunk = (lane & 7) ^ srow;

    const unsigned short* gAbase = Xb + (size_t)(m0 + w*32 + srow)*DIM + gchunk*8;
    const unsigned short* gBbase = W  + (size_t)(w*32 + srow)*DIM      + gchunk*8;

    f32x4 acc[4][4];
    #pragma unroll
    for (int i = 0; i < 4; i++)
        #pragma unroll
        for (int j = 0; j < 4; j++)
            acc[i][j] = (f32x4){0.f, 0.f, 0.f, 0.f};

    #define STAGE(KT, BUF)                                                        \
        {                                                                         \
            _Pragma("unroll")                                                     \
            for (int c = 0; c < 4; c++) {                                         \
                __builtin_amdgcn_global_load_lds(                                 \
                    (const __attribute__((address_space(1))) unsigned int*)       \
                        (gAbase + (size_t)(c*8)*DIM + (KT)*64),                   \
                    (__attribute__((address_space(3))) unsigned int*)             \
                        &Sm[(BUF)*2][(w*32 + c*8)*64], 16, 0, 0);                 \
                __builtin_amdgcn_global_load_lds(                                 \
                    (const __attribute__((address_space(1))) unsigned int*)       \
                        (gBbase + (size_t)(c*8)*DIM + (KT)*64),                   \
                    (__attribute__((address_space(3))) unsigned int*)             \
                        &Sm[(BUF)*2 + 1][(w*32 + c*8)*64], 16, 0, 0);             \
            }                                                                     \
        }

    STAGE(0, 0);
    __syncthreads();

    #pragma unroll
    for (int kt = 0; kt < 12; ++kt) {
        if (kt + 1 < 12) STAGE(kt + 1, (kt + 1) & 1);

        const unsigned short* As = &Sm[(kt & 1) * 2][0];
        const unsigned short* Bs = &Sm[(kt & 1) * 2 + 1][0];

        #pragma unroll
        for (int kk = 0; kk < 2; kk++) {
            const int ch = kk*4 + quad;
            short8 af[4], bf_[4];
            #pragma unroll
            for (int i = 0; i < 4; i++) {
                const int row = wm + i*16 + l15;
                af[i]  = *(const short8*)&As[row*64 + ((ch ^ (row & 7)) << 3)];
            }
            #pragma unroll
            for (int j = 0; j < 4; j++) {
                const int row = wn + j*16 + l15;
                bf_[j] = *(const short8*)&Bs[row*64 + ((ch ^ (row & 7)) << 3)];
            }
            #pragma unroll
            for (int i = 0; i < 4; i++)
                #pragma unroll
                for (int j = 0; j < 4; j++)
                    acc[i][j] = __builtin_amdgcn_mfma_f32_16x16x32_bf16(af[i], bf_[j], acc[i][j], 0, 0, 0);
        }
        __syncthreads();
    }
    #undef STAGE

    // ---- epilogue: acc(+bias) -> LDS [128][136] -> coalesced 16B stores ----
    unsigned short* Cs = &Sm[0][0];
    #pragma unroll
    for (int j = 0; j < 4; j++) {
        const int col = wn + j*16 + l15;
        const float bv_ = bias[n0 + col];
        #pragma unroll
        for (int i = 0; i < 4; i++) {
            #pragma unroll
            for (int r = 0; r < 4; r++) {
                const int row = wm + i*16 + quad*4 + r;
                Cs[row*136 + col] = f2bf(acc[i][j][r] + bv_);
            }
        }
    }
    __syncthreads();
    #pragma unroll
    for (int u = 0; u < 8; u++) {
        const int idx = u*256 + t;
        const int row = idx >> 4, ch = idx & 15;
        short8 v = *(const short8*)&Cs[row*136 + ch*8];
        *(short8*)&out[(size_t)(m0 + row)*DIM + n0 + ch*8] = v;
    }
}

// XOR-swizzled LDS addressing for 64x64-ushort tiles.
__device__ __forceinline__ int swz(int row, int u) {
    return row*64 + ((u ^ (row & 7)) << 3);
}

// ---------------------------------------------------------------------------
// K2: branch-1 token attention (REVERTED to measured-best scatter-READ V
// staging; grid=(300,8)).  V-path post-mortem, three failed alternatives:
//  - HBM vt side-buffer (R6): +6.5us qkv write cost, no attn1 gain
//  - in-LDS transpose + 3rd barrier (R7): serialized kt loop, 60->74.6us
//  - LDS u16 scatter-WRITE (R14): 17.2M bank conflicts (lanes sharing a row
//    write stride-1024B = same bank, 8-way), 59->91us
// The scalar-gather reads are lane-coalesced (lane=d) and remain cheapest.
// ---------------------------------------------------------------------------
__global__ __launch_bounds__(256) void attn1_mfma(
    const unsigned short* __restrict__ qb, const unsigned short* __restrict__ kb,
    const unsigned short* __restrict__ vb, float* __restrict__ a1p)
{
    int whs = blockIdx.x;
    const int chunk = blockIdx.y;
    const int si = whs % SHOT;  whs /= SHOT;
    const int hi = whs % HEADS; whs /= HEADS;
    const int wi = whs;
    const size_t baseRow = (size_t)(wi*SHOT + si) * LSEQ;
    const int colBase = hi * HD;

    __shared__ __align__(16) unsigned short Qs[64*64];
    __shared__ __align__(16) unsigned short Ks[64*64];
    __shared__ __align__(16) unsigned short Vt[64*64];
    __shared__ __align__(16) unsigned short Pb[64*64];
    __shared__ float cmaxs[4][64];

    const int t = threadIdx.x;
    const int w = t >> 6;
    const int lane = t & 63;
    const int quad = lane >> 4;
    const int l15 = lane & 15;

    #pragma unroll
    for (int p = 0; p < 2; p++) {
        int idx = p*256 + t;
        int row = idx >> 3, u = idx & 7;
        *(short8*)&Qs[swz(row, u)] =
            *(const short8*)&qb[(baseRow + chunk*64 + row)*DIM + colBase + u*8];
    }

    float l_part[4] = {0.f, 0.f, 0.f, 0.f};   // per-lane partial row sums
    f32x4 o_acc[4];
    #pragma unroll
    for (int d = 0; d < 4; d++) o_acc[d] = (f32x4){0.f, 0.f, 0.f, 0.f};

    for (int kt = 0; kt < 8; kt++) {
        __syncthreads();
        #pragma unroll
        for (int p = 0; p < 2; p++) {
            int idx = p*256 + t;
            int row = idx >> 3, u = idx & 7;
            *(short8*)&Ks[swz(row, u)] =
                *(const short8*)&kb[(baseRow + kt*64 + row)*DIM + colBase + u*8];
        }
        #pragma unroll
        for (int p = 0; p < 2; p++) {
            int idx = p*256 + t;
            int d = idx & 63, lc = idx >> 6;
            unsigned short tmp[8];
            #pragma unroll
            for (int jj = 0; jj < 8; jj++)
                tmp[jj] = vb[(baseRow + kt*64 + lc*8 + jj)*DIM + colBase + d];
            *(short8*)&Vt[swz(d, lc)] = *(const short8*)tmp;
        }
        __syncthreads();

        // S = Q K^T
        f32x4 s_acc[4];
        #pragma unroll
        for (int nt = 0; nt < 4; nt++) s_acc[nt] = (f32x4){0.f, 0.f, 0.f, 0.f};
        short8 aq[2];
        #pragma unroll
        for (int kk = 0; kk < 2; kk++)
            aq[kk] = *(const short8*)&Qs[swz(w*16 + l15, kk*4 + quad)];
        #pragma unroll
        for (int kk = 0; kk < 2; kk++) {
            #pragma unroll
            for (int nt = 0; nt < 4; nt++) {
                short8 bk_ = *(const short8*)&Ks[swz(nt*16 + l15, kk*4 + quad)];
                s_acc[nt] = __builtin_amdgcn_mfma_f32_16x16x32_bf16(aq[kk], bk_, s_acc[nt], 0, 0, 0);
            }
        }

        // e = exp(s*SCALE), no max-subtraction; accumulate per-lane row sums
        #pragma unroll
        for (int nt = 0; nt < 4; nt++) {
            #pragma unroll
            for (int r = 0; r < 4; r++) {
                float e = __expf(s_acc[nt][r] * SCALE);
                s_acc[nt][r] = e;
                l_part[r] += e;
            }
        }

        // write P (bf16) into wave-private Pb rows
        #pragma unroll
        for (int nt = 0; nt < 4; nt++) {
            int ucol = nt*2 + (l15 >> 3);
            int cofs = l15 & 7;
            #pragma unroll
            for (int r = 0; r < 4; r++) {
                int row = w*16 + quad*4 + r;
                Pb[swz(row, ucol) + cofs] = f2bf(s_acc[nt][r]);
            }
        }

        // O += P V
        short8 ap[2];
        #pragma unroll
        for (int kk = 0; kk < 2; kk++)
            ap[kk] = *(const short8*)&Pb[swz(w*16 + l15, kk*4 + quad)];
        #pragma unroll
        for (int kk = 0; kk < 2; kk++) {
            #pragma unroll
            for (int dt = 0; dt < 4; dt++) {
                short8 bv_ = *(const short8*)&Vt[swz(dt*16 + l15, kk*4 + quad)];
                o_acc[dt] = __builtin_amdgcn_mfma_f32_16x16x32_bf16(ap[kk], bv_, o_acc[dt], 0, 0, 0);
            }
        }
    }

    // single end-of-block row-sum reduction over the 16 lanes sharing quad
    float l_tot[4];
    #pragma unroll
    for (int r = 0; r < 4; r++) {
        float s = l_part[r];
        #pragma unroll
        for (int off = 1; off < 16; off <<= 1) s += __shfl_xor(s, off);
        l_tot[r] = s;
    }

    float cm[4];
    #pragma unroll
    for (int dt = 0; dt < 4; dt++) {
        float mx = -1e30f;
        #pragma unroll
        for (int r = 0; r < 4; r++) mx = fmaxf(mx, o_acc[dt][r] / l_tot[r]);
        mx = fmaxf(mx, __shfl_xor(mx, 16));
        mx = fmaxf(mx, __shfl_xor(mx, 32));
        cm[dt] = mx;
    }
    if (quad == 0) {
        #pragma unroll
        for (int dt = 0; dt < 4; dt++) cmaxs[w][dt*16 + l15] = cm[dt];
    }
    __syncthreads();
    if (t < 64) {
        float mx = fmaxf(fmaxf(cmaxs[0][t], cmaxs[1][t]), fmaxf(cmaxs[2][t], cmaxs[3][t]));
        a1p[((size_t)((wi*HEADS + hi)*SHOT + si)*8 + chunk)*64 + t] = mx;
    }
}

// ---------------------------------------------------------------------------
// K3a: branch-2 scores: one block per (wh, si, tt) pair, grid = 1500,
// block = 256, direct pre-scaled SSC output.
// ---------------------------------------------------------------------------
__global__ __launch_bounds__(256) void attn2_scores(
    const unsigned short* __restrict__ qb, const unsigned short* __restrict__ kb,
    float* __restrict__ SSC)
{
    const int bid = blockIdx.x;          // 0..1499
    const int wh = bid / 25, pr = bid % 25;
    const int wi = wh / HEADS, hi = wh % HEADS;
    const int si = pr / 5, tt = pr % 5;
    const int t = threadIdx.x;
    const int w = t >> 6, lane = t & 63;
    const int doct = lane & 7;
    const int lgrp = w*8 + (lane >> 3);   // 0..31
    const int colB = hi*HD + doct*8;

    const unsigned short* qrow = qb + (size_t)(wi*SHOT+si)*LSEQ*DIM + colB;
    const unsigned short* krow = kb + (size_t)(wi*SHOT+tt)*LSEQ*DIM + colB;

    float acc[8] = {};
    #pragma unroll
    for (int it = 0; it < 16; it++) {
        const int l = lgrp + it*32;
        short8 q8 = *(const short8*)(qrow + (size_t)l*DIM);
        short8 k8 = *(const short8*)(krow + (size_t)l*DIM);
        #pragma unroll
        for (int j = 0; j < 8; j++)
            acc[j] += bf2f((unsigned short)q8[j]) * bf2f((unsigned short)k8[j]);
    }
    // intra-wave reduce across the 8 lgrp slots sharing a doct
    #pragma unroll
    for (int off = 8; off < 64; off <<= 1)
        #pragma unroll
        for (int j = 0; j < 8; j++)
            acc[j] += __shfl_xor(acc[j], off);

    __shared__ float ws[4][8][8];
    if (lane < 8) {
        #pragma unroll
        for (int j = 0; j < 8; j++) ws[w][lane][j] = acc[j];
    }
    __syncthreads();
    if (t < 64) {
        const int dct = t >> 3, j = t & 7;
        float s = ws[0][dct][j] + ws[1][dct][j] + ws[2][dct][j] + ws[3][dct][j];
        SSC[(size_t)(wh*25 + pr)*64 + dct*8 + j] = s * SCALE;
    }
}

// ---------------------------------------------------------------------------
// K3b: finish softmax + partial weighted-max.  grid=(60,8), block=320.
// ---------------------------------------------------------------------------
__global__ __launch_bounds__(320) void attn2_pmax(
    const float* __restrict__ SSC, const unsigned short* __restrict__ vb,
    float* __restrict__ P2)
{
    const int wh = blockIdx.x, ch = blockIdx.y;
    const int wi = wh / HEADS, hi = wh % HEADS;
    const int t = threadIdx.x;
    const int si = t / 64;
    const int r  = t & 63;
    const int doct = r >> 3, lsub = r & 7;

    __shared__ float ssc[SHOT*SHOT*HD];   // scaled scores [si][tt][d]

    for (int e = t; e < SHOT*SHOT*HD; e += 320)
        ssc[e] = SSC[(size_t)wh*(SHOT*SHOT*HD) + e];
    __syncthreads();

    // softmax over tt (scores tiny -> no max subtraction)
    float wgt[SHOT][8];
    #pragma unroll
    for (int j = 0; j < 8; j++) {
        const int d = doct*8 + j;
        float sum = 0.f;
        #pragma unroll
        for (int tt = 0; tt < SHOT; tt++) {
            float e = __expf(ssc[(si*SHOT + tt)*HD + d]);
            wgt[tt][j] = e; sum += e;
        }
        const float inv = 1.f / sum;
        #pragma unroll
        for (int tt = 0; tt < SHOT; tt++) wgt[tt][j] *= inv;
    }

    const int colB = hi*HD + doct*8;
    float m[8];
    #pragma unroll
    for (int j = 0; j < 8; j++) m[j] = -1e30f;

    #pragma unroll 4
    for (int lc = 0; lc < 8; lc++) {
        const int l = ch*64 + lsub*8 + lc;
        float val[8] = {};
        #pragma unroll
        for (int tt = 0; tt < SHOT; tt++) {
            short8 v8 = *(const short8*)(vb + ((size_t)(wi*SHOT+tt)*LSEQ + l)*DIM + colB);
            #pragma unroll
            for (int j = 0; j < 8; j++)
                val[j] += wgt[tt][j] * bf2f((unsigned short)v8[j]);
        }
        #pragma unroll
        for (int j = 0; j < 8; j++) m[j] = fmaxf(m[j], val[j]);
    }

    #pragma unroll
    for (int off = 1; off < 8; off <<= 1)
        #pragma unroll
        for (int j = 0; j < 8; j++) m[j] = fmaxf(m[j], __shfl_xor(m[j], off));

    if (lsub == 0) {
        #pragma unroll
        for (int j = 0; j < 8; j++)
            P2[((size_t)(wh*SHOT + si)*64 + doct*8 + j)*8 + ch] = m[j];
    }
}

// ---------------------------------------------------------------------------
// K4: per-(w,s) chunk-max reduce + dual LN + tanh + wp-dot.  grid=25.
// P2 chunk-max vectorized as 2x float4.
// ---------------------------------------------------------------------------
__global__ __launch_bounds__(256) void combine(
    const float* __restrict__ a1p, const float* __restrict__ P2,
    const float* __restrict__ gamma, const float* __restrict__ beta,
    const float* __restrict__ wp, const float* __restrict__ bp,
    float* __restrict__ attn_ws, float* __restrict__ logits)
{
    const int wi = blockIdx.x / SHOT;
    const int si = blockIdx.x % SHOT;
    const int t  = threadIdx.x;

    __shared__ float row1[DIM];
    __shared__ float row2[DIM];
    __shared__ float rbuf[4][4];

    for (int j = t; j < DIM; j += 256) {
        int h = j / HD, d = j % HD;
        const float* p1 = a1p + ((size_t)((wi*HEADS + h)*SHOT + si) * 8) * 64 + d;
        float mx = -1e30f;
        #pragma unroll
        for (int c = 0; c < 8; c++) mx = fmaxf(mx, p1[c * 64]);
        row1[j] = mx;
        const float4* p2v = (const float4*)(P2 + ((size_t)((wi*HEADS + h)*SHOT + si)*64 + d)*8);
        const float4 pa = p2v[0], pb = p2v[1];
        float mx2 = fmaxf(fmaxf(fmaxf(pa.x, pa.y), fmaxf(pa.z, pa.w)),
                          fmaxf(fmaxf(pb.x, pb.y), fmaxf(pb.z, pb.w)));
        row2[j] = mx2;
    }
    __syncthreads();

    float s1 = 0, q1 = 0, s2 = 0, q2 = 0;
    for (int j = t; j < DIM; j += 256) {
        float x1 = row1[j]; s1 += x1; q1 += x1*x1;
        float x2 = row2[j]; s2 += x2; q2 += x2*x2;
    }
    #pragma unroll
    for (int off = 32; off > 0; off >>= 1) {
        s1 += __shfl_down(s1, off); q1 += __shfl_down(q1, off);
        s2 += __shfl_down(s2, off); q2 += __shfl_down(q2, off);
    }
    const int wid = t / 64, lane = t % 64;
    if (lane == 0) { rbuf[wid][0] = s1; rbuf[wid][1] = q1; rbuf[wid][2] = s2; rbuf[wid][3] = q2; }
    __syncthreads();
    if (t == 0) {
        float a = 0, b = 0, c = 0, dd = 0;
        #pragma unroll
        for (int i = 0; i < 4; i++) { a += rbuf[i][0]; b += rbuf[i][1]; c += rbuf[i][2]; dd += rbuf[i][3]; }
        rbuf[0][0] = a; rbuf[0][1] = b; rbuf[0][2] = c; rbuf[0][3] = dd;
    }
    __syncthreads();
    const float mean1 = rbuf[0][0] / (float)DIM;
    const float var1  = rbuf[0][1] / (float)DIM - mean1*mean1;
    const float mean2 = rbuf[0][2] / (float)DIM;
    const float var2  = rbuf[0][3] / (float)DIM - mean2*mean2;
    const float inv1 = rsqrtf(var1 + 1e-5f);
    const float inv2 = rsqrtf(var2 + 1e-5f);

    float dotp = 0.0f;
    for (int j = t; j < DIM; j += 256) {
        float v1 = (row1[j] - mean1) * inv1 * gamma[j] + beta[j];
        float v2 = (row2[j] - mean2) * inv2 * gamma[j] + beta[j];
        float at = 0.5f * (v1 + v2);
        attn_ws[(size_t)(wi*SHOT + si) * DIM + j] = at;
        dotp += tanhf(at) * wp[j];
    }
    #pragma unroll
    for (int off = 32; off > 0; off >>= 1) dotp += __shfl_down(dotp, off);
    __syncthreads();
    if (lane == 0) rbuf[wid][0] = dotp;
    __syncthreads();
    if (t == 0)
        logits[wi*SHOT + si] = rbuf[0][0] + rbuf[1][0] + rbuf[2][0] + rbuf[3][0] + bp[0];
}

// ---------------------------------------------------------------------------
// K5: shot-softmax + folded output projection.  grid = 192 x 256.
// ---------------------------------------------------------------------------
__global__ __launch_bounds__(256) void outproj(
    const float* __restrict__ attn_ws, const float* __restrict__ logits,
    const float* __restrict__ Wo, const float* __restrict__ bo,
    float* __restrict__ out)
{
    const int t = threadIdx.x;
    __shared__ __align__(16) float P[WAY][DIM];

    // shot-softmax weights (all threads compute all 25; logits broadcast via L1)
    float swt[WAY][SHOT];
    #pragma unroll
    for (int w5 = 0; w5 < WAY; w5++) {
        float lg[SHOT];
        float mx = -1e30f;
        #pragma unroll
        for (int s = 0; s < SHOT; s++) { lg[s] = logits[w5*SHOT + s]; mx = fmaxf(mx, lg[s]); }
        float sum = 0.f;
        #pragma unroll
        for (int s = 0; s < SHOT; s++) { lg[s] = __expf(lg[s] - mx); sum += lg[s]; }
        const float inv = 1.f / sum;
        #pragma unroll
        for (int s = 0; s < SHOT; s++) swt[w5][s] = lg[s] * inv;
    }

    // stage weighted prototypes: P[w][d] = sum_s swt[w][s] * attn_ws[w*5+s][d]
    #pragma unroll
    for (int c = 0; c < 3; c++) {
        const int d = c*256 + t;
        #pragma unroll
        for (int w5 = 0; w5 < WAY; w5++) {
            float a = 0.f;
            #pragma unroll
            for (int s = 0; s < SHOT; s++)
                a += swt[w5][s] * attn_ws[(size_t)(w5*SHOT + s)*DIM + d];
            P[w5][d] = a;
        }
    }
    __syncthreads();

    // each wave: one output column j, dotted against all 5 ways
    const int wid = t >> 6, lane = t & 63;
    const int j = blockIdx.x * 4 + wid;   // 192*4 = 768

    float acc[WAY] = {0.f, 0.f, 0.f, 0.f, 0.f};
    #pragma unroll
    for (int c = 0; c < 3; c++) {
        const int d = c*256 + lane*4;
        const float4 wo = *(const float4*)&Wo[(size_t)j*DIM + d];
        #pragma unroll
        for (int w5 = 0; w5 < WAY; w5++) {
            const float4 p = *(const float4*)&P[w5][d];
            acc[w5] += p.x*wo.x + p.y*wo.y + p.z*wo.z + p.w*wo.w;
        }
    }
    #pragma unroll
    for (int off = 32; off > 0; off >>= 1)
        #pragma unroll
        for (int w5 = 0; w5 < WAY; w5++)
            acc[w5] += __shfl_down(acc[w5], off);

    if (lane == 0) {
        const float b5 = 5.0f * bo[j];
        #pragma unroll
        for (int w5 = 0; w5 < WAY; w5++)
            out[(size_t)w5*DIM + j] = acc[w5] + b5;
    }
}

// ---------------------------------------------------------------------------
extern "C" void kernel_launch(void* const* d_in, const int* in_sizes, int n_in,
                              void* d_out, int out_size, void* d_ws, size_t ws_size,
                              hipStream_t stream) {
    const float* X     = (const float*)d_in[0];
    const float* Wq    = (const float*)d_in[1];
    const float* bq    = (const float*)d_in[2];
    const float* Wk    = (const float*)d_in[3];
    const float* bk    = (const float*)d_in[4];
    const float* Wv    = (const float*)d_in[5];
    const float* bv    = (const float*)d_in[6];
    const float* gamma = (const float*)d_in[7];
    const float* beta  = (const float*)d_in[8];
    const float* wp    = (const float*)d_in[9];
    const float* bp    = (const float*)d_in[10];
    const float* Wo    = (const float*)d_in[11];
    const float* bo    = (const float*)d_in[12];
    float* out = (float*)d_out;

    unsigned short* Xb   = (unsigned short*)d_ws;
    unsigned short* Wb   = Xb + NXEL;
    unsigned short* qkvb = Wb + 3*NWEL;
    unsigned short* qb = qkvb;
    unsigned short* kb = qkvb + NXEL;
    unsigned short* vb = qkvb + 2*NXEL;

    float* a1p    = (float*)(qkvb + 3*NXEL);
    float* SSC    = a1p + (size_t)WAY*HEADS*SHOT*8*64;
    float* P2     = SSC + (size_t)WAY*HEADS*SHOT*SHOT*64*8;
    float* attn_b = P2 + (size_t)WAY*HEADS*SHOT*64*8;
    float* logits = attn_b + (size_t)WAY*SHOT*DIM;

    // K0: one cast launch
    const int castN = NX4 + 3*NW4;
    cast_all<<<(castN + 255)/256, 256, 0, stream>>>(X, Wq, Wk, Wv, Xb, Wb);

    // K1: QKV projection
    qkv_mfma<<<1800, 256, 0, stream>>>(Xb, Wb, bq, bk, bv, qkvb);

    // K2: branch-1 attention
    dim3 g2(WAY*HEADS*SHOT, 8);
    attn1_mfma<<<g2, 256, 0, stream>>>(qb, kb, vb, a1p);

    // K3: branch-2 attention
    attn2_scores<<<1500, 256, 0, stream>>>(qb, kb, SSC);
    dim3 g3(WAY*HEADS, 8);
    attn2_pmax<<<g3, 320, 0, stream>>>(SSC, vb, P2);

    // K4/K5
    combine<<<WAY*SHOT, 256, 0, stream>>>(a1p, P2, gamma, beta, wp, bp, attn_b, logits);
    outproj<<<192, 256, 0, stream>>>(attn_b, logits, Wo, bo, out);
}